// Round 7
// baseline (190.162 us; speedup 1.0000x reference)
//
#include <hip/hip_runtime.h>
#include <cstdint>
#include <cstddef>

using u16 = unsigned short;
using u32 = unsigned int;
using u64 = unsigned long long;

typedef short bf16x8 __attribute__((ext_vector_type(8)));
typedef float f32x4 __attribute__((ext_vector_type(4)));
typedef float f4a __attribute__((ext_vector_type(4), aligned(4)));   // 4B-aligned vector load

constexpr int N0 = 8192;
constexpr int N1 = 4096;
constexpr int N2 = 2048;
constexpr int COUT = 128;
constexpr int KNB = 16;

__device__ __forceinline__ float bf2f(u16 v) { return __uint_as_float(((u32)v) << 16); }
__device__ __forceinline__ u16 f2bf(float f) {  // round-to-nearest-even
    u32 u = __float_as_uint(f);
    return (u16)((u + 0x7fffu + ((u >> 16) & 1u)) >> 16);
}
__device__ __forceinline__ void cvt8(const float* __restrict__ src, u16* __restrict__ dst, int e) {
    float t0[8];
    *(float4*)t0 = *(const float4*)(src + e);
    *(float4*)(t0 + 4) = *(const float4*)(src + e + 4);
    u16 o[8];
#pragma unroll
    for (int q = 0; q < 8; ++q) o[q] = f2bf(t0[q]);
    *(uint4*)(dst + e) = *(uint4*)o;
}

// Distances must match the np reference bit-exactly: no FMA contraction, sequential sum.
__device__ __forceinline__ float dist2s(float cx, float cy, float cz,
                                        float px, float py, float pz) {
#pragma clang fp contract(off)
    float dx = cx - px;
    float dy = cy - py;
    float dz = cz - pz;
    float s = dx * dx;
    s = s + dy * dy;
    s = s + dz * dz;
    return s;
}

// ---- DPP cross-lane helpers (VALU pipe, no LDS traffic) ----
template <int CTRL>
__device__ __forceinline__ u64 dpp64(u64 v) {
    int lo = (int)(u32)v, hi = (int)(u32)(v >> 32);
    int plo = __builtin_amdgcn_update_dpp(0, lo, CTRL, 0xF, 0xF, true);
    int phi = __builtin_amdgcn_update_dpp(0, hi, CTRL, 0xF, 0xF, true);
    return (((u64)(u32)phi) << 32) | (u32)plo;
}
// row_shr:1 with bound_ctrl=1: lane L gets lane L-1; lane 0 of each 16-row gets 0.
__device__ __forceinline__ u64 dpp_prev_u64(u64 v) { return dpp64<0x111>(v); }

// wave-uniform broadcast via v_readlane (scalar result, no ds_bpermute on the chain)
__device__ __forceinline__ u32 rdlane(u32 v, int l) {
    return (u32)__builtin_amdgcn_readlane((int)v, l);
}

// load 4 consecutive candidate points (xyz each) into q[12]
template <int PSTRIDE>
__device__ __forceinline__ void load4(const float* __restrict__ p, float* q) {
    if constexpr (PSTRIDE == 3) {       // 12 contiguous floats -> 3x dwordx4 (4B-aligned)
        f4a v0 = *(const f4a*)p, v1 = *(const f4a*)(p + 4), v2 = *(const f4a*)(p + 8);
        q[0] = v0.x; q[1] = v0.y; q[2]  = v0.z;
        q[3] = v0.w; q[4] = v1.x; q[5]  = v1.y;
        q[6] = v1.z; q[7] = v1.w; q[8]  = v2.x;
        q[9] = v2.y; q[10] = v2.z; q[11] = v2.w;
    } else {                            // stride 6: per-point dwordx4, xyz used
        f4a v0 = *(const f4a*)p,                  v1 = *(const f4a*)(p + PSTRIDE);
        f4a v2 = *(const f4a*)(p + 2 * PSTRIDE),  v3 = *(const f4a*)(p + 3 * PSTRIDE);
        q[0] = v0.x; q[1] = v0.y; q[2]  = v0.z;
        q[3] = v1.x; q[4] = v1.y; q[5]  = v1.z;
        q[6] = v2.x; q[7] = v2.y; q[8]  = v2.z;
        q[9] = v3.x; q[10] = v3.y; q[11] = v3.z;
    }
}

// ---------------- KNN scan, one wave, TWO centers, 256 candidates/step (4 per lane).
// Sorted-16 list in lanes 0..15 as u64 (d2_bits<<32)|idx — exact order + low-index tie-break.
// Same keys/inserts as the R1/R4/R6-proven scan (insertion order is irrelevant to the
// sorted-16 set); only the per-step batching and load vectorization changed.
template <int PSTRIDE>
__device__ __forceinline__ void knn_scan(const float* __restrict__ P,
                                         int c0row, int c1row, int cnt,
                                         int lane, u64& rk0, u64& rk1) {
    const float* c0p = P + (size_t)c0row * PSTRIDE;
    const float* c1p = P + (size_t)c1row * PSTRIDE;
    float c0x = c0p[0], c0y = c0p[1], c0z = c0p[2];
    float c1x = c1p[0], c1y = c1p[1], c1z = c1p[2];

    u64 key0, key1;
    {   // warm start: bitonic-sort first 64 points (xor 1/2/8 via DPP)
        const float* pp = P + (size_t)lane * PSTRIDE;
        float px = pp[0], py = pp[1], pz = pp[2];
        u64 k0 = (((u64)__float_as_uint(dist2s(c0x, c0y, c0z, px, py, pz))) << 32) | (u32)lane;
        u64 k1 = (((u64)__float_as_uint(dist2s(c1x, c1y, c1z, px, py, pz))) << 32) | (u32)lane;
#pragma unroll
        for (int kk = 2; kk <= 64; kk <<= 1)
#pragma unroll
            for (int jj = kk >> 1; jj > 0; jj >>= 1) {
                u64 o0, o1;
                if (jj == 1)      { o0 = dpp64<0xB1>(k0);  o1 = dpp64<0xB1>(k1); }
                else if (jj == 2) { o0 = dpp64<0x4E>(k0);  o1 = dpp64<0x4E>(k1); }
                else if (jj == 8) { o0 = dpp64<0x128>(k0); o1 = dpp64<0x128>(k1); }
                else              { o0 = __shfl_xor(k0, jj, 64); o1 = __shfl_xor(k1, jj, 64); }
                bool keepmin = (((lane & jj) == 0) == ((lane & kk) == 0));
                k0 = keepmin ? ((o0 < k0) ? o0 : k0) : ((o0 > k0) ? o0 : k0);
                k1 = keepmin ? ((o1 < k1) ? o1 : k1) : ((o1 > k1) ? o1 : k1);
            }
        key0 = k0; key1 = k1;
    }
    u32 cut0 = rdlane((u32)(key0 >> 32), 15);
    u32 cut1 = rdlane((u32)(key1 >> 32), 15);

    {   // half-step: candidates [64,128), one per lane
        const float* pp = P + (size_t)(64 + lane) * PSTRIDE;
        float px = pp[0], py = pp[1], pz = pp[2];
        u32 d0 = __float_as_uint(dist2s(c0x, c0y, c0z, px, py, pz));
        u32 d1 = __float_as_uint(dist2s(c1x, c1y, c1z, px, py, pz));
        u64 ball0 = __ballot(d0 <= cut0);
        u64 ball1 = __ballot(d1 <= cut1);
        while (ball0 | ball1) {
            if (ball0) {
                int src = __ffsll((unsigned long long)ball0) - 1;
                ball0 &= ball0 - 1;
                u64 nk = (((u64)rdlane(d0, src)) << 32) | (u32)(64 + src);
                u64 prev = dpp_prev_u64(key0);
                key0 = (nk < key0) ? ((nk < prev) ? prev : nk) : key0;
            }
            if (ball1) {
                int src = __ffsll((unsigned long long)ball1) - 1;
                ball1 &= ball1 - 1;
                u64 nk = (((u64)rdlane(d1, src)) << 32) | (u32)(64 + src);
                u64 prev = dpp_prev_u64(key1);
                key1 = (nk < key1) ? ((nk < prev) ? prev : nk) : key1;
            }
        }
        cut0 = rdlane((u32)(key0 >> 32), 15);
        cut1 = rdlane((u32)(key1 >> 32), 15);
    }

    // main loop: 256 candidates/step (4 per lane) from 128; one 128-candidate tail step.
    int nmain = (cnt - 256) >> 8;
    const float* curp = P + (size_t)(128 + 4 * lane) * PSTRIDE;
    float pf[12];
    load4<PSTRIDE>(curp, pf);
    for (int s = 0; s < nmain; ++s) {
        float c[12];
#pragma unroll
        for (int q = 0; q < 12; ++q) c[q] = pf[q];
        curp += 256 * PSTRIDE;
        if (s + 1 < nmain) load4<PSTRIDE>(curp, pf);
        int sb = 128 + (s << 8);
        u32 d0[4], d1[4];
#pragma unroll
        for (int j = 0; j < 4; ++j) {
            d0[j] = __float_as_uint(dist2s(c0x, c0y, c0z, c[3 * j], c[3 * j + 1], c[3 * j + 2]));
            d1[j] = __float_as_uint(dist2s(c1x, c1y, c1z, c[3 * j], c[3 * j + 1], c[3 * j + 2]));
        }
        u64 B0[4], B1[4];
#pragma unroll
        for (int j = 0; j < 4; ++j) {
            B0[j] = __ballot(d0[j] <= cut0);
            B1[j] = __ballot(d1[j] <= cut1);
        }
        while (B0[0] | B0[1] | B0[2] | B0[3] | B1[0] | B1[1] | B1[2] | B1[3]) {
#pragma unroll
            for (int j = 0; j < 4; ++j) {
                if (B0[j]) {
                    int src = __ffsll((unsigned long long)B0[j]) - 1;
                    B0[j] &= B0[j] - 1;
                    u64 nk = (((u64)rdlane(d0[j], src)) << 32) | (u32)(sb + 4 * src + j);
                    u64 prev = dpp_prev_u64(key0);
                    key0 = (nk < key0) ? ((nk < prev) ? prev : nk) : key0;
                }
                if (B1[j]) {
                    int src = __ffsll((unsigned long long)B1[j]) - 1;
                    B1[j] &= B1[j] - 1;
                    u64 nk = (((u64)rdlane(d1[j], src)) << 32) | (u32)(sb + 4 * src + j);
                    u64 prev = dpp_prev_u64(key1);
                    key1 = (nk < key1) ? ((nk < prev) ? prev : nk) : key1;
                }
            }
        }
        cut0 = rdlane((u32)(key0 >> 32), 15);
        cut1 = rdlane((u32)(key1 >> 32), 15);
    }
    {   // tail: 128 candidates (2 per lane) at tb = 128 + nmain*256
        int tb = 128 + (nmain << 8);
        const float* pa = P + (size_t)(tb + 2 * lane) * PSTRIDE;
        float cax = pa[0], cay = pa[1], caz = pa[2];
        float cbx = pa[PSTRIDE], cby = pa[PSTRIDE + 1], cbz = pa[PSTRIDE + 2];
        u32 da0 = __float_as_uint(dist2s(c0x, c0y, c0z, cax, cay, caz));
        u32 da1 = __float_as_uint(dist2s(c1x, c1y, c1z, cax, cay, caz));
        u32 db0 = __float_as_uint(dist2s(c0x, c0y, c0z, cbx, cby, cbz));
        u32 db1 = __float_as_uint(dist2s(c1x, c1y, c1z, cbx, cby, cbz));
        u64 ba0 = __ballot(da0 <= cut0);
        u64 bb0 = __ballot(db0 <= cut0);
        u64 ba1 = __ballot(da1 <= cut1);
        u64 bb1 = __ballot(db1 <= cut1);
        while (ba0 | bb0 | ba1 | bb1) {
            if (ba0) {
                int src = __ffsll((unsigned long long)ba0) - 1;
                ba0 &= ba0 - 1;
                u64 nk = (((u64)rdlane(da0, src)) << 32) | (u32)(tb + 2 * src);
                u64 prev = dpp_prev_u64(key0);
                key0 = (nk < key0) ? ((nk < prev) ? prev : nk) : key0;
            }
            if (ba1) {
                int src = __ffsll((unsigned long long)ba1) - 1;
                ba1 &= ba1 - 1;
                u64 nk = (((u64)rdlane(da1, src)) << 32) | (u32)(tb + 2 * src);
                u64 prev = dpp_prev_u64(key1);
                key1 = (nk < key1) ? ((nk < prev) ? prev : nk) : key1;
            }
            if (bb0) {
                int src = __ffsll((unsigned long long)bb0) - 1;
                bb0 &= bb0 - 1;
                u64 nk = (((u64)rdlane(db0, src)) << 32) | (u32)(tb + 2 * src + 1);
                u64 prev = dpp_prev_u64(key0);
                key0 = (nk < key0) ? ((nk < prev) ? prev : nk) : key0;
            }
            if (bb1) {
                int src = __ffsll((unsigned long long)bb1) - 1;
                bb1 &= bb1 - 1;
                u64 nk = (((u64)rdlane(db1, src)) << 32) | (u32)(tb + 2 * src + 1);
                u64 prev = dpp_prev_u64(key1);
                key1 = (nk < key1) ? ((nk < prev) ? prev : nk) : key1;
            }
        }
    }
    rk0 = key0; rk1 = key1;
}

// ---------------- dispatch 1: knn1 (1024) + knn2 (512) + prep (752) = 2288 blocks --
__global__ __launch_bounds__(256)
void knn_prep_kernel(const float* __restrict__ pos0, const float* __restrict__ ch0,
                     const float* __restrict__ W1, const float* __restrict__ W2,
                     const float* __restrict__ Wres,
                     int* __restrict__ knn1, int* __restrict__ knn2,
                     u16* __restrict__ ch0b, u16* __restrict__ W1b,
                     u16* __restrict__ W2b, u16* __restrict__ Wresb,
                     float* __restrict__ pos_out) {
    int blk = blockIdx.x, tid = threadIdx.x;
    int w = tid >> 6, lane = tid & 63;
    if (blk < 1024) {
        // knn1: one wave per center-pair, full 8192-candidate scan (stride 3 floats)
        int wave = blk * 4 + w;
        int batch = wave >> 11, pj = wave & 2047;
        const float* P = pos0 + (size_t)batch * N0 * 3;
        u64 key0, key1;
        knn_scan<3>(P, 4 * pj, 4 * pj + 2, N0, lane, key0, key1);
        if (lane < 16) {
            knn1[((size_t)(batch * N1 + 2 * pj)) * KNB + lane] = (int)(u32)key0;
            knn1[((size_t)(batch * N1 + 2 * pj + 1)) * KNB + lane] = (int)(u32)key1;
        }
    } else if (blk < 1536) {
        // knn2: one wave per center-pair, full 4096-candidate scan over level-1 rows (stride 6)
        int wave = (blk - 1024) * 4 + w;
        int batch = wave >> 10, pj = wave & 1023;
        const float* P = pos0 + (size_t)batch * N0 * 3;
        u64 key0, key1;
        knn_scan<6>(P, 4 * pj, 4 * pj + 2, N1, lane, key0, key1);
        if (lane < 16) {
            knn2[((size_t)(batch * N2 + 2 * pj)) * KNB + lane] = (int)(u32)key0;
            knn2[((size_t)(batch * N2 + 2 * pj + 1)) * KNB + lane] = (int)(u32)key1;
        }
    } else if (blk < 2048) {          // ch0 -> bf16 (1,048,576 elems)
        cvt8(ch0, ch0b, ((blk - 1536) * 256 + tid) * 8);
    } else if (blk < 2112) {          // W1 -> bf16 (131,072)
        cvt8(W1, W1b, ((blk - 2048) * 256 + tid) * 8);
    } else if (blk < 2240) {          // W2 -> bf16 (262,144)
        cvt8(W2, W2b, ((blk - 2112) * 256 + tid) * 8);
    } else if (blk < 2272) {          // Wres[c][o] -> Wresb[o][c] bf16 (8192 elems)
        int t = (blk - 2240) * 256 + tid;
        int o = t >> 6, c = t & 63;
        Wresb[o * 64 + c] = f2bf(Wres[(size_t)c * COUT + o]);
    } else {                          // pos_out copy: 4096 rows (16 blocks)
        int t = (blk - 2272) * 256 + tid;
        int b = t >> 11, r = t & 2047;
        const float* s = pos0 + ((size_t)(b * N0 + r * 4)) * 3;
        float* d = pos_out + ((size_t)(b * N2 + r)) * 3;
        d[0] = s[0]; d[1] = s[1]; d[2] = s[2];
    }
}

// ---------------- dispatch 2: conv1 W-direct (512 blk) — R4/R6 verbatim ------------
__global__ __launch_bounds__(256)
void conv1_kernel(const u16* __restrict__ ch0b, const int* __restrict__ knn1,
                  const u16* __restrict__ W1b, const u16* __restrict__ Wresb,
                  const float* __restrict__ b1, const float* __restrict__ bres,
                  const float* __restrict__ g1, const float* __restrict__ be1,
                  u16* __restrict__ ch1b, u16* __restrict__ res1b) {
    __shared__ u16 As[2][16][72];     // double-buffered A tile: 16 rows x 64 bf16 (+8 pad)
    __shared__ int knnr[16][16];
    __shared__ float red[16][4][2];
    __shared__ float cb[128], cg[128], cbe[128], cbr[128];

    int blk = blockIdx.x, tid = threadIdx.x;
    int b = blk >> 8, g = blk & 255;
    int jbase = g * 16;

    if (tid < 128) { cb[tid] = b1[tid]; cg[tid] = g1[tid]; cbe[tid] = be1[tid]; cbr[tid] = bres[tid]; }
    {   // 256 knn ints, 1 per thread
        int r = tid >> 4, k = tid & 15;
        knnr[r][k] = knn1[((size_t)(b * N1 + jbase + r)) * KNB + k];
    }
    __syncthreads();

    int w = tid >> 6, lane = tid & 63, quad = lane >> 4, l15 = lane & 15;
    int wcol = w * 32;
    int ar = tid >> 4, ap = tid & 15;     // A staging: 16 rows x 16 chunks of 8B

    f32x4 acc[2] = {{0,0,0,0},{0,0,0,0}};
    f32x4 racc[2] = {{0,0,0,0},{0,0,0,0}};

    // per-lane W fragment bases (cols wcol+l15 and wcol+16+l15)
    const u16* w0base = W1b + (size_t)(wcol + l15) * 1024 + quad * 8;
    const u16* w1base = W1b + (size_t)(wcol + 16 + l15) * 1024 + quad * 8;

    // prologue: prefetch chunk 0
    uint2 aR = *((const uint2*)(ch0b + ((size_t)(b * N0 + knnr[ar][0])) * 64) + ap);
    uint4 wcur[4] = { *(const uint4*)w0base, *(const uint4*)(w0base + 32),
                      *(const uint4*)w1base, *(const uint4*)(w1base + 32) };

    int pb = 0;
    for (int kn = 0; kn < 17; ++kn) {     // 16 neighbor chunks + 1 residual chunk
        *(uint2*)&As[pb][ar][ap * 4] = aR;
        __syncthreads();
        uint4 wnxt[4];
        if (kn < 16) {  // prefetch next chunk (kn==15 -> residual sources)
            int nidx = (kn < 15) ? knnr[ar][kn + 1] : 2 * (jbase + ar);
            aR = *((const uint2*)(ch0b + ((size_t)(b * N0 + nidx)) * 64) + ap);
            if (kn < 15) {
                const u16* p0 = w0base + (kn + 1) * 64;
                const u16* p1 = w1base + (kn + 1) * 64;
                wnxt[0] = *(const uint4*)p0; wnxt[1] = *(const uint4*)(p0 + 32);
                wnxt[2] = *(const uint4*)p1; wnxt[3] = *(const uint4*)(p1 + 32);
            } else {
                const u16* p0 = Wresb + (size_t)(wcol + l15) * 64 + quad * 8;
                const u16* p1 = Wresb + (size_t)(wcol + 16 + l15) * 64 + quad * 8;
                wnxt[0] = *(const uint4*)p0; wnxt[1] = *(const uint4*)(p0 + 32);
                wnxt[2] = *(const uint4*)p1; wnxt[3] = *(const uint4*)(p1 + 32);
            }
        }
        if (kn < 16) {
#pragma unroll
            for (int ks = 0; ks < 2; ++ks) {
                bf16x8 af = *(const bf16x8*)&As[pb][l15][ks * 32 + quad * 8];
                acc[0] = __builtin_amdgcn_mfma_f32_16x16x32_bf16(af, *(const bf16x8*)&wcur[ks], acc[0], 0, 0, 0);
                acc[1] = __builtin_amdgcn_mfma_f32_16x16x32_bf16(af, *(const bf16x8*)&wcur[2 + ks], acc[1], 0, 0, 0);
            }
        } else {
#pragma unroll
            for (int ks = 0; ks < 2; ++ks) {
                bf16x8 af = *(const bf16x8*)&As[pb][l15][ks * 32 + quad * 8];
                racc[0] = __builtin_amdgcn_mfma_f32_16x16x32_bf16(af, *(const bf16x8*)&wcur[ks], racc[0], 0, 0, 0);
                racc[1] = __builtin_amdgcn_mfma_f32_16x16x32_bf16(af, *(const bf16x8*)&wcur[2 + ks], racc[1], 0, 0, 0);
            }
        }
        if (kn < 16) {
            wcur[0] = wnxt[0]; wcur[1] = wnxt[1]; wcur[2] = wnxt[2]; wcur[3] = wnxt[3];
        }
        pb ^= 1;
    }

    // epilogue: bias + LN(+SiLU) on conv acc; bias on residual; both stored bf16
    float x[2][4], s[4] = {0,0,0,0}, ss[4] = {0,0,0,0};
#pragma unroll
    for (int reg = 0; reg < 4; ++reg)
#pragma unroll
        for (int nt = 0; nt < 2; ++nt) {
            int col = wcol + nt * 16 + l15;
            float v = acc[nt][reg] + cb[col];
            x[nt][reg] = v;
            s[reg] += v; ss[reg] += v * v;
        }
#pragma unroll
    for (int m = 1; m < 16; m <<= 1)
#pragma unroll
        for (int reg = 0; reg < 4; ++reg) {
            s[reg] += __shfl_xor(s[reg], m, 64);
            ss[reg] += __shfl_xor(ss[reg], m, 64);
        }
    if (l15 == 0) {
#pragma unroll
        for (int reg = 0; reg < 4; ++reg) {
            red[quad * 4 + reg][w][0] = s[reg];
            red[quad * 4 + reg][w][1] = ss[reg];
        }
    }
    __syncthreads();
    float mu[4], rs[4];
#pragma unroll
    for (int reg = 0; reg < 4; ++reg) {
        int row = quad * 4 + reg;
        float S = red[row][0][0] + red[row][1][0] + red[row][2][0] + red[row][3][0];
        float SS = red[row][0][1] + red[row][1][1] + red[row][2][1] + red[row][3][1];
        mu[reg] = S * (1.f / 128.f);
        float var = fmaxf(SS * (1.f / 128.f) - mu[reg] * mu[reg], 0.f);
        rs[reg] = 1.f / sqrtf(var + 1e-5f);
    }
#pragma unroll
    for (int nt = 0; nt < 2; ++nt)
#pragma unroll
        for (int reg = 0; reg < 4; ++reg) {
            int col = wcol + nt * 16 + l15;
            int row = quad * 4 + reg;
            size_t off = ((size_t)(b * N1 + jbase + row)) * COUT + col;
            float y = (x[nt][reg] - mu[reg]) * rs[reg] * cg[col] + cbe[col];
            ch1b[off] = f2bf(y / (1.f + __expf(-y)));
            res1b[off] = f2bf(racc[nt][reg] + cbr[col]);
        }
}

// ---------------- dispatch 3: conv2 W-direct, K=2048, 512 thr (8 waves), M=16 ------
__global__ __launch_bounds__(512)
void conv2_kernel(const u16* __restrict__ ch1b, const int* __restrict__ knn2,
                  const u16* __restrict__ W2b, const float* __restrict__ b2,
                  const float* __restrict__ g2, const float* __restrict__ be2,
                  const u16* __restrict__ res1b, float* __restrict__ ch_out) {
    __shared__ u16 As[2][16][136];    // double-buffered A tile: 16 rows x 128 bf16 (+8 pad)
    __shared__ int knnr[16][16];
    __shared__ float red[16][8][2];
    __shared__ float cb[128], cg[128], cbe[128];

    int tid = threadIdx.x;            // 0..511
    int b = blockIdx.x >> 7, g = blockIdx.x & 127;
    int ibase = g * 16;

    if (tid < 128) { cb[tid] = b2[tid]; cg[tid] = g2[tid]; cbe[tid] = be2[tid]; }
    if (tid < 256) {
        int r = tid >> 4, k = tid & 15;
        knnr[r][k] = knn2[((size_t)(b * N2 + ibase + r)) * KNB + k];
    }
    __syncthreads();

    int w = tid >> 6, lane = tid & 63, quad = lane >> 4, l15 = lane & 15;
    int wcol = w * 16;
    int ar = tid >> 5, ap = tid & 31;     // A staging: 16 rows x 32 chunks of 8B

    f32x4 acc = {0, 0, 0, 0};

    // per-lane W fragment base (col wcol+l15); frag(ks) at kn: base + kn*128 + ks*32
    const u16* wbase = W2b + (size_t)(wcol + l15) * 2048 + quad * 8;

    uint2 aR = *((const uint2*)(ch1b + ((size_t)(b * N1 + knnr[ar][0])) * COUT) + ap);
    uint4 wcur[4] = { *(const uint4*)wbase, *(const uint4*)(wbase + 32),
                      *(const uint4*)(wbase + 64), *(const uint4*)(wbase + 96) };

    int pb = 0;
    for (int kn = 0; kn < 16; ++kn) {
        *(uint2*)&As[pb][ar][ap * 4] = aR;
        __syncthreads();
        uint4 wnxt[4];
        if (kn < 15) {
            aR = *((const uint2*)(ch1b + ((size_t)(b * N1 + knnr[ar][kn + 1])) * COUT) + ap);
            const u16* p = wbase + (kn + 1) * 128;
            wnxt[0] = *(const uint4*)p;        wnxt[1] = *(const uint4*)(p + 32);
            wnxt[2] = *(const uint4*)(p + 64); wnxt[3] = *(const uint4*)(p + 96);
        }
#pragma unroll
        for (int ks = 0; ks < 4; ++ks) {
            bf16x8 af = *(const bf16x8*)&As[pb][l15][ks * 32 + quad * 8];
            acc = __builtin_amdgcn_mfma_f32_16x16x32_bf16(af, *(const bf16x8*)&wcur[ks], acc, 0, 0, 0);
        }
        if (kn < 15) {
            wcur[0] = wnxt[0]; wcur[1] = wnxt[1]; wcur[2] = wnxt[2]; wcur[3] = wnxt[3];
        }
        pb ^= 1;
    }

    float x[4], s[4], ss[4];
#pragma unroll
    for (int reg = 0; reg < 4; ++reg) {
        int col = wcol + l15;
        float v = acc[reg] + cb[col];
        x[reg] = v; s[reg] = v; ss[reg] = v * v;
    }
#pragma unroll
    for (int m = 1; m < 16; m <<= 1)
#pragma unroll
        for (int reg = 0; reg < 4; ++reg) {
            s[reg] += __shfl_xor(s[reg], m, 64);
            ss[reg] += __shfl_xor(ss[reg], m, 64);
        }
    if (l15 == 0) {
#pragma unroll
        for (int reg = 0; reg < 4; ++reg) {
            red[quad * 4 + reg][w][0] = s[reg];
            red[quad * 4 + reg][w][1] = ss[reg];
        }
    }
    __syncthreads();
#pragma unroll
    for (int reg = 0; reg < 4; ++reg) {
        int row = quad * 4 + reg;
        float S = 0.f, SS = 0.f;
#pragma unroll
        for (int t = 0; t < 8; ++t) { S += red[row][t][0]; SS += red[row][t][1]; }
        float mu = S * (1.f / 128.f);
        float var = fmaxf(SS * (1.f / 128.f) - mu * mu, 0.f);
        float rs = 1.f / sqrtf(var + 1e-5f);
        int col = wcol + l15;
        int i = ibase + row;
        float y = (x[reg] - mu) * rs * cg[col] + cbe[col];
        float sl = y / (1.f + __expf(-y));
        float rv = bf2f(res1b[((size_t)(b * N1 + 2 * i)) * COUT + col]);
        ch_out[((size_t)(b * N2 + i)) * COUT + col] = sl + rv;
    }
}

extern "C" void kernel_launch(void* const* d_in, const int* in_sizes, int n_in,
                              void* d_out, int out_size, void* d_ws, size_t ws_size,
                              hipStream_t stream) {
    const float* pos0 = (const float*)d_in[0];
    const float* ch0  = (const float*)d_in[1];
    const float* W1   = (const float*)d_in[2];
    const float* b1   = (const float*)d_in[3];
    const float* Wres = (const float*)d_in[4];
    const float* bres = (const float*)d_in[5];
    const float* W2   = (const float*)d_in[6];
    const float* b2   = (const float*)d_in[7];
    const float* g1   = (const float*)d_in[8];
    const float* be1  = (const float*)d_in[9];
    const float* g2   = (const float*)d_in[10];
    const float* be2  = (const float*)d_in[11];
    float* out = (float*)d_out;

    char* ws = (char*)d_ws;
    int*  knn1  = (int*)(ws);                      // 524288
    int*  knn2  = (int*)(ws + 524288);             // 262144
    u16*  ch0b  = (u16*)(ws + 786432);             // 2097152
    u16*  W1b   = (u16*)(ws + 2883584);            // 262144
    u16*  W2b   = (u16*)(ws + 3145728);            // 524288
    u16*  Wresb = (u16*)(ws + 3670016);            // 16384
    u16*  ch1b  = (u16*)(ws + 3686400);            // 2097152
    u16*  res1b = (u16*)(ws + 5783552);            // 2097152  (total ~7.9 MB)

    float* pos_out = out;          // [2,2048,3] fp32
    float* ch_out  = out + 12288;  // [2,2048,128] fp32

    knn_prep_kernel<<<2288, 256, 0, stream>>>(pos0, ch0, W1, W2, Wres,
                                              knn1, knn2, ch0b, W1b, W2b, Wresb, pos_out);
    conv1_kernel<<<512, 256, 0, stream>>>(ch0b, knn1, W1b, Wresb, b1, bres, g1, be1,
                                          ch1b, res1b);
    conv2_kernel<<<256, 512, 0, stream>>>(ch1b, knn2, W2b, b2, g2, be2, res1b, ch_out);
}

// Round 8
// 184.005 us; speedup vs baseline: 1.0335x; 1.0335x over previous
//
#include <hip/hip_runtime.h>
#include <cstdint>
#include <cstddef>

using u16 = unsigned short;
using u32 = unsigned int;
using u64 = unsigned long long;

typedef short bf16x8 __attribute__((ext_vector_type(8)));
typedef float f32x4 __attribute__((ext_vector_type(4)));

constexpr int N0 = 8192;
constexpr int N1 = 4096;
constexpr int N2 = 2048;
constexpr int COUT = 128;
constexpr int KNB = 16;

__device__ __forceinline__ float bf2f(u16 v) { return __uint_as_float(((u32)v) << 16); }
__device__ __forceinline__ u16 f2bf(float f) {  // round-to-nearest-even
    u32 u = __float_as_uint(f);
    return (u16)((u + 0x7fffu + ((u >> 16) & 1u)) >> 16);
}
__device__ __forceinline__ void cvt8(const float* __restrict__ src, u16* __restrict__ dst, int e) {
    float t0[8];
    *(float4*)t0 = *(const float4*)(src + e);
    *(float4*)(t0 + 4) = *(const float4*)(src + e + 4);
    u16 o[8];
#pragma unroll
    for (int q = 0; q < 8; ++q) o[q] = f2bf(t0[q]);
    *(uint4*)(dst + e) = *(uint4*)o;
}

// Distances must match the np reference bit-exactly: no FMA contraction, sequential sum.
__device__ __forceinline__ float dist2s(float cx, float cy, float cz,
                                        float px, float py, float pz) {
#pragma clang fp contract(off)
    float dx = cx - px;
    float dy = cy - py;
    float dz = cz - pz;
    float s = dx * dx;
    s = s + dy * dy;
    s = s + dz * dz;
    return s;
}

// ---- DPP cross-lane helpers (VALU pipe, no LDS traffic) ----
template <int CTRL>
__device__ __forceinline__ u64 dpp64(u64 v) {
    int lo = (int)(u32)v, hi = (int)(u32)(v >> 32);
    int plo = __builtin_amdgcn_update_dpp(0, lo, CTRL, 0xF, 0xF, true);
    int phi = __builtin_amdgcn_update_dpp(0, hi, CTRL, 0xF, 0xF, true);
    return (((u64)(u32)phi) << 32) | (u32)plo;
}
// row_shr:1 with bound_ctrl=1: lane L gets lane L-1; lane 0 of each 16-row gets 0.
__device__ __forceinline__ u64 dpp_prev_u64(u64 v) { return dpp64<0x111>(v); }

// wave-uniform broadcast via v_readlane (scalar result, no ds_bpermute on the chain)
__device__ __forceinline__ u32 rdlane(u32 v, int l) {
    return (u32)__builtin_amdgcn_readlane((int)v, l);
}

// ---------------- KNN scan, one wave, TWO centers, 128 candidates/step (2 per lane).
// Sorted-16 list in lanes 0..15 as u64 (d2_bits<<32)|idx — exact order + low-index tie-break.
// PROVEN best at R6 (183 us total, knn_prep 66.6). R5 (2-way split) and R7 (4 cand/lane)
// both regressed: this structure is at its balance point — do not touch.
template <int PSTRIDE>
__device__ __forceinline__ void knn_scan(const float* __restrict__ P,
                                         int c0row, int c1row, int cnt,
                                         int lane, u64& rk0, u64& rk1) {
    const float* c0p = P + (size_t)c0row * PSTRIDE;
    const float* c1p = P + (size_t)c1row * PSTRIDE;
    float c0x = c0p[0], c0y = c0p[1], c0z = c0p[2];
    float c1x = c1p[0], c1y = c1p[1], c1z = c1p[2];

    u64 key0, key1;
    {   // warm start: bitonic-sort first 64 points (xor 1/2/8 via DPP)
        const float* pp = P + (size_t)lane * PSTRIDE;
        float px = pp[0], py = pp[1], pz = pp[2];
        u64 k0 = (((u64)__float_as_uint(dist2s(c0x, c0y, c0z, px, py, pz))) << 32) | (u32)lane;
        u64 k1 = (((u64)__float_as_uint(dist2s(c1x, c1y, c1z, px, py, pz))) << 32) | (u32)lane;
#pragma unroll
        for (int kk = 2; kk <= 64; kk <<= 1)
#pragma unroll
            for (int jj = kk >> 1; jj > 0; jj >>= 1) {
                u64 o0, o1;
                if (jj == 1)      { o0 = dpp64<0xB1>(k0);  o1 = dpp64<0xB1>(k1); }
                else if (jj == 2) { o0 = dpp64<0x4E>(k0);  o1 = dpp64<0x4E>(k1); }
                else if (jj == 8) { o0 = dpp64<0x128>(k0); o1 = dpp64<0x128>(k1); }
                else              { o0 = __shfl_xor(k0, jj, 64); o1 = __shfl_xor(k1, jj, 64); }
                bool keepmin = (((lane & jj) == 0) == ((lane & kk) == 0));
                k0 = keepmin ? ((o0 < k0) ? o0 : k0) : ((o0 > k0) ? o0 : k0);
                k1 = keepmin ? ((o1 < k1) ? o1 : k1) : ((o1 > k1) ? o1 : k1);
            }
        key0 = k0; key1 = k1;
    }
    u32 cut0 = rdlane((u32)(key0 >> 32), 15);
    u32 cut1 = rdlane((u32)(key1 >> 32), 15);

    {   // half-step: candidates [64,128), one per lane
        const float* pp = P + (size_t)(64 + lane) * PSTRIDE;
        float px = pp[0], py = pp[1], pz = pp[2];
        u32 d0 = __float_as_uint(dist2s(c0x, c0y, c0z, px, py, pz));
        u32 d1 = __float_as_uint(dist2s(c1x, c1y, c1z, px, py, pz));
        u64 ball0 = __ballot(d0 <= cut0);
        u64 ball1 = __ballot(d1 <= cut1);
        while (ball0 | ball1) {
            if (ball0) {
                int src = __ffsll((unsigned long long)ball0) - 1;
                ball0 &= ball0 - 1;
                u64 nk = (((u64)rdlane(d0, src)) << 32) | (u32)(64 + src);
                u64 prev = dpp_prev_u64(key0);
                key0 = (nk < key0) ? ((nk < prev) ? prev : nk) : key0;
            }
            if (ball1) {
                int src = __ffsll((unsigned long long)ball1) - 1;
                ball1 &= ball1 - 1;
                u64 nk = (((u64)rdlane(d1, src)) << 32) | (u32)(64 + src);
                u64 prev = dpp_prev_u64(key1);
                key1 = (nk < key1) ? ((nk < prev) ? prev : nk) : key1;
            }
        }
        cut0 = rdlane((u32)(key0 >> 32), 15);
        cut1 = rdlane((u32)(key1 >> 32), 15);
    }

    // main loop: 128 candidates/step (2 per lane), starting at 128.
    constexpr int STEPF = 128 * PSTRIDE;
    int nstep = (cnt - 128) >> 7;
    const float* cur = P + (size_t)(128 + 2 * lane) * PSTRIDE;
    float ax = cur[0], ay = cur[1], az = cur[2];
    float bx = cur[PSTRIDE], by = cur[PSTRIDE + 1], bz = cur[PSTRIDE + 2];
    for (int s = 0; s < nstep; ++s) {
        float cax = ax, cay = ay, caz = az, cbx = bx, cby = by, cbz = bz;
        cur += STEPF;
        if (s + 1 < nstep) {
            ax = cur[0]; ay = cur[1]; az = cur[2];
            bx = cur[PSTRIDE]; by = cur[PSTRIDE + 1]; bz = cur[PSTRIDE + 2];
        }
        int sb = 128 + (s << 7);
        u32 da0 = __float_as_uint(dist2s(c0x, c0y, c0z, cax, cay, caz));
        u32 da1 = __float_as_uint(dist2s(c1x, c1y, c1z, cax, cay, caz));
        u32 db0 = __float_as_uint(dist2s(c0x, c0y, c0z, cbx, cby, cbz));
        u32 db1 = __float_as_uint(dist2s(c1x, c1y, c1z, cbx, cby, cbz));
        u64 ba0 = __ballot(da0 <= cut0);
        u64 bb0 = __ballot(db0 <= cut0);
        u64 ba1 = __ballot(da1 <= cut1);
        u64 bb1 = __ballot(db1 <= cut1);
        while (ba0 | bb0 | ba1 | bb1) {   // two independent key chains, 4 ballot streams
            if (ba0) {
                int src = __ffsll((unsigned long long)ba0) - 1;
                ba0 &= ba0 - 1;
                u64 nk = (((u64)rdlane(da0, src)) << 32) | (u32)(sb + 2 * src);
                u64 prev = dpp_prev_u64(key0);
                key0 = (nk < key0) ? ((nk < prev) ? prev : nk) : key0;
            }
            if (ba1) {
                int src = __ffsll((unsigned long long)ba1) - 1;
                ba1 &= ba1 - 1;
                u64 nk = (((u64)rdlane(da1, src)) << 32) | (u32)(sb + 2 * src);
                u64 prev = dpp_prev_u64(key1);
                key1 = (nk < key1) ? ((nk < prev) ? prev : nk) : key1;
            }
            if (bb0) {
                int src = __ffsll((unsigned long long)bb0) - 1;
                bb0 &= bb0 - 1;
                u64 nk = (((u64)rdlane(db0, src)) << 32) | (u32)(sb + 2 * src + 1);
                u64 prev = dpp_prev_u64(key0);
                key0 = (nk < key0) ? ((nk < prev) ? prev : nk) : key0;
            }
            if (bb1) {
                int src = __ffsll((unsigned long long)bb1) - 1;
                bb1 &= bb1 - 1;
                u64 nk = (((u64)rdlane(db1, src)) << 32) | (u32)(sb + 2 * src + 1);
                u64 prev = dpp_prev_u64(key1);
                key1 = (nk < key1) ? ((nk < prev) ? prev : nk) : key1;
            }
        }
        cut0 = rdlane((u32)(key0 >> 32), 15);
        cut1 = rdlane((u32)(key1 >> 32), 15);
    }
    rk0 = key0; rk1 = key1;
}

// ---------------- dispatch 1: knn1 (1024) + knn2 (512) + prep (752) = 2288 blocks --
// R6-proven routing: knn2's waves + prep's memory-bound copies fill knn1's idle issue
// slots; conv1 dispatch has no knn tail.
__global__ __launch_bounds__(256)
void knn_prep_kernel(const float* __restrict__ pos0, const float* __restrict__ ch0,
                     const float* __restrict__ W1, const float* __restrict__ W2,
                     const float* __restrict__ Wres,
                     int* __restrict__ knn1, int* __restrict__ knn2,
                     u16* __restrict__ ch0b, u16* __restrict__ W1b,
                     u16* __restrict__ W2b, u16* __restrict__ Wresb,
                     float* __restrict__ pos_out) {
    int blk = blockIdx.x, tid = threadIdx.x;
    int w = tid >> 6, lane = tid & 63;
    if (blk < 1024) {
        // knn1: one wave per center-pair, full 8192-candidate scan (stride 3 floats)
        int wave = blk * 4 + w;
        int batch = wave >> 11, pj = wave & 2047;
        const float* P = pos0 + (size_t)batch * N0 * 3;
        u64 key0, key1;
        knn_scan<3>(P, 4 * pj, 4 * pj + 2, N0, lane, key0, key1);
        if (lane < 16) {
            knn1[((size_t)(batch * N1 + 2 * pj)) * KNB + lane] = (int)(u32)key0;
            knn1[((size_t)(batch * N1 + 2 * pj + 1)) * KNB + lane] = (int)(u32)key1;
        }
    } else if (blk < 1536) {
        // knn2: one wave per center-pair, full 4096-candidate scan over level-1 rows (stride 6)
        int wave = (blk - 1024) * 4 + w;
        int batch = wave >> 10, pj = wave & 1023;
        const float* P = pos0 + (size_t)batch * N0 * 3;
        u64 key0, key1;
        knn_scan<6>(P, 4 * pj, 4 * pj + 2, N1, lane, key0, key1);
        if (lane < 16) {
            knn2[((size_t)(batch * N2 + 2 * pj)) * KNB + lane] = (int)(u32)key0;
            knn2[((size_t)(batch * N2 + 2 * pj + 1)) * KNB + lane] = (int)(u32)key1;
        }
    } else if (blk < 2048) {          // ch0 -> bf16 (1,048,576 elems)
        cvt8(ch0, ch0b, ((blk - 1536) * 256 + tid) * 8);
    } else if (blk < 2112) {          // W1 -> bf16 (131,072)
        cvt8(W1, W1b, ((blk - 2048) * 256 + tid) * 8);
    } else if (blk < 2240) {          // W2 -> bf16 (262,144)
        cvt8(W2, W2b, ((blk - 2112) * 256 + tid) * 8);
    } else if (blk < 2272) {          // Wres[c][o] -> Wresb[o][c] bf16 (8192 elems)
        int t = (blk - 2240) * 256 + tid;
        int o = t >> 6, c = t & 63;
        Wresb[o * 64 + c] = f2bf(Wres[(size_t)c * COUT + o]);
    } else {                          // pos_out copy: 4096 rows (16 blocks)
        int t = (blk - 2272) * 256 + tid;
        int b = t >> 11, r = t & 2047;
        const float* s = pos0 + ((size_t)(b * N0 + r * 4)) * 3;
        float* d = pos_out + ((size_t)(b * N2 + r)) * 3;
        d[0] = s[0]; d[1] = s[1]; d[2] = s[2];
    }
}

// ---------------- dispatch 2: conv1 W-direct, 512 blk x 512 thr (8 waves) ----------
// R8: 8 waves/block (16 waves/CU, double the R6 pool) to hide the gather-load latency
// on the K-loop critical path. Each wave owns 16 output cols; W fragments load straight
// global->VGPR; only the gathered A-tile (2 KB) is LDS-staged, double-buffered,
// ONE barrier per K-chunk.
__global__ __launch_bounds__(512)
void conv1_kernel(const u16* __restrict__ ch0b, const int* __restrict__ knn1,
                  const u16* __restrict__ W1b, const u16* __restrict__ Wresb,
                  const float* __restrict__ b1, const float* __restrict__ bres,
                  const float* __restrict__ g1, const float* __restrict__ be1,
                  u16* __restrict__ ch1b, u16* __restrict__ res1b) {
    __shared__ u16 As[2][16][72];     // double-buffered A tile: 16 rows x 64 bf16 (+8 pad)
    __shared__ int knnr[16][16];
    __shared__ float red[16][8][2];
    __shared__ float cb[128], cg[128], cbe[128], cbr[128];

    int blk = blockIdx.x, tid = threadIdx.x;   // 0..511
    int b = blk >> 8, g = blk & 255;
    int jbase = g * 16;

    if (tid < 128) { cb[tid] = b1[tid]; cg[tid] = g1[tid]; cbe[tid] = be1[tid]; cbr[tid] = bres[tid]; }
    if (tid < 256) {   // 256 knn ints
        int r = tid >> 4, k = tid & 15;
        knnr[r][k] = knn1[((size_t)(b * N1 + jbase + r)) * KNB + k];
    }
    __syncthreads();

    int w = tid >> 6, lane = tid & 63, quad = lane >> 4, l15 = lane & 15;
    int wcol = w * 16;
    int ar = tid >> 5, ap = tid & 31;     // A staging: 16 rows x 32 chunks of 4B

    f32x4 acc = {0, 0, 0, 0};
    f32x4 racc = {0, 0, 0, 0};

    // per-lane W fragment base (col wcol+l15); frag(ks) at kn: base + kn*64 + ks*32
    const u16* wbase = W1b + (size_t)(wcol + l15) * 1024 + quad * 8;

    // prologue: prefetch chunk 0
    u32 aR = *((const u32*)(ch0b + ((size_t)(b * N0 + knnr[ar][0])) * 64) + ap);
    uint4 wcur[2] = { *(const uint4*)wbase, *(const uint4*)(wbase + 32) };

    int pb = 0;
    for (int kn = 0; kn < 17; ++kn) {     // 16 neighbor chunks + 1 residual chunk
        *(u32*)&As[pb][ar][ap * 2] = aR;
        __syncthreads();
        uint4 wnxt[2];
        if (kn < 16) {  // prefetch next chunk (kn==15 -> residual sources)
            int nidx = (kn < 15) ? knnr[ar][kn + 1] : 2 * (jbase + ar);
            aR = *((const u32*)(ch0b + ((size_t)(b * N0 + nidx)) * 64) + ap);
            if (kn < 15) {
                const u16* p = wbase + (kn + 1) * 64;
                wnxt[0] = *(const uint4*)p; wnxt[1] = *(const uint4*)(p + 32);
            } else {
                const u16* p = Wresb + (size_t)(wcol + l15) * 64 + quad * 8;
                wnxt[0] = *(const uint4*)p; wnxt[1] = *(const uint4*)(p + 32);
            }
        }
        if (kn < 16) {
#pragma unroll
            for (int ks = 0; ks < 2; ++ks) {
                bf16x8 af = *(const bf16x8*)&As[pb][l15][ks * 32 + quad * 8];
                acc = __builtin_amdgcn_mfma_f32_16x16x32_bf16(af, *(const bf16x8*)&wcur[ks], acc, 0, 0, 0);
            }
        } else {
#pragma unroll
            for (int ks = 0; ks < 2; ++ks) {
                bf16x8 af = *(const bf16x8*)&As[pb][l15][ks * 32 + quad * 8];
                racc = __builtin_amdgcn_mfma_f32_16x16x32_bf16(af, *(const bf16x8*)&wcur[ks], racc, 0, 0, 0);
            }
        }
        if (kn < 16) { wcur[0] = wnxt[0]; wcur[1] = wnxt[1]; }
        pb ^= 1;
    }

    // epilogue: bias + LN(+SiLU) on conv acc; bias on residual; both stored bf16
    float x[4], s[4], ss[4];
#pragma unroll
    for (int reg = 0; reg < 4; ++reg) {
        int col = wcol + l15;
        float v = acc[reg] + cb[col];
        x[reg] = v; s[reg] = v; ss[reg] = v * v;
    }
#pragma unroll
    for (int m = 1; m < 16; m <<= 1)
#pragma unroll
        for (int reg = 0; reg < 4; ++reg) {
            s[reg] += __shfl_xor(s[reg], m, 64);
            ss[reg] += __shfl_xor(ss[reg], m, 64);
        }
    if (l15 == 0) {
#pragma unroll
        for (int reg = 0; reg < 4; ++reg) {
            red[quad * 4 + reg][w][0] = s[reg];
            red[quad * 4 + reg][w][1] = ss[reg];
        }
    }
    __syncthreads();
#pragma unroll
    for (int reg = 0; reg < 4; ++reg) {
        int row = quad * 4 + reg;
        float S = 0.f, SS = 0.f;
#pragma unroll
        for (int t = 0; t < 8; ++t) { S += red[row][t][0]; SS += red[row][t][1]; }
        float mu = S * (1.f / 128.f);
        float var = fmaxf(SS * (1.f / 128.f) - mu * mu, 0.f);
        float rs = 1.f / sqrtf(var + 1e-5f);
        int col = wcol + l15;
        size_t off = ((size_t)(b * N1 + jbase + row)) * COUT + col;
        float y = (x[reg] - mu) * rs * cg[col] + cbe[col];
        ch1b[off] = f2bf(y / (1.f + __expf(-y)));
        res1b[off] = f2bf(racc[reg] + cbr[col]);
    }
}

// ---------------- dispatch 3: conv2 W-direct, K=2048, 512 thr (8 waves), M=16 ------
__global__ __launch_bounds__(512)
void conv2_kernel(const u16* __restrict__ ch1b, const int* __restrict__ knn2,
                  const u16* __restrict__ W2b, const float* __restrict__ b2,
                  const float* __restrict__ g2, const float* __restrict__ be2,
                  const u16* __restrict__ res1b, float* __restrict__ ch_out) {
    __shared__ u16 As[2][16][136];    // double-buffered A tile: 16 rows x 128 bf16 (+8 pad)
    __shared__ int knnr[16][16];
    __shared__ float red[16][8][2];
    __shared__ float cb[128], cg[128], cbe[128];

    int tid = threadIdx.x;            // 0..511
    int b = blockIdx.x >> 7, g = blockIdx.x & 127;
    int ibase = g * 16;

    if (tid < 128) { cb[tid] = b2[tid]; cg[tid] = g2[tid]; cbe[tid] = be2[tid]; }
    if (tid < 256) {
        int r = tid >> 4, k = tid & 15;
        knnr[r][k] = knn2[((size_t)(b * N2 + ibase + r)) * KNB + k];
    }
    __syncthreads();

    int w = tid >> 6, lane = tid & 63, quad = lane >> 4, l15 = lane & 15;
    int wcol = w * 16;
    int ar = tid >> 5, ap = tid & 31;     // A staging: 16 rows x 32 chunks of 8B

    f32x4 acc = {0, 0, 0, 0};

    // per-lane W fragment base (col wcol+l15); frag(ks) at kn: base + kn*128 + ks*32
    const u16* wbase = W2b + (size_t)(wcol + l15) * 2048 + quad * 8;

    uint2 aR = *((const uint2*)(ch1b + ((size_t)(b * N1 + knnr[ar][0])) * COUT) + ap);
    uint4 wcur[4] = { *(const uint4*)wbase, *(const uint4*)(wbase + 32),
                      *(const uint4*)(wbase + 64), *(const uint4*)(wbase + 96) };

    int pb = 0;
    for (int kn = 0; kn < 16; ++kn) {
        *(uint2*)&As[pb][ar][ap * 4] = aR;
        __syncthreads();
        uint4 wnxt[4];
        if (kn < 15) {
            aR = *((const uint2*)(ch1b + ((size_t)(b * N1 + knnr[ar][kn + 1])) * COUT) + ap);
            const u16* p = wbase + (kn + 1) * 128;
            wnxt[0] = *(const uint4*)p;        wnxt[1] = *(const uint4*)(p + 32);
            wnxt[2] = *(const uint4*)(p + 64); wnxt[3] = *(const uint4*)(p + 96);
        }
#pragma unroll
        for (int ks = 0; ks < 4; ++ks) {
            bf16x8 af = *(const bf16x8*)&As[pb][l15][ks * 32 + quad * 8];
            acc = __builtin_amdgcn_mfma_f32_16x16x32_bf16(af, *(const bf16x8*)&wcur[ks], acc, 0, 0, 0);
        }
        if (kn < 15) {
            wcur[0] = wnxt[0]; wcur[1] = wnxt[1]; wcur[2] = wnxt[2]; wcur[3] = wnxt[3];
        }
        pb ^= 1;
    }

    float x[4], s[4], ss[4];
#pragma unroll
    for (int reg = 0; reg < 4; ++reg) {
        int col = wcol + l15;
        float v = acc[reg] + cb[col];
        x[reg] = v; s[reg] = v; ss[reg] = v * v;
    }
#pragma unroll
    for (int m = 1; m < 16; m <<= 1)
#pragma unroll
        for (int reg = 0; reg < 4; ++reg) {
            s[reg] += __shfl_xor(s[reg], m, 64);
            ss[reg] += __shfl_xor(ss[reg], m, 64);
        }
    if (l15 == 0) {
#pragma unroll
        for (int reg = 0; reg < 4; ++reg) {
            red[quad * 4 + reg][w][0] = s[reg];
            red[quad * 4 + reg][w][1] = ss[reg];
        }
    }
    __syncthreads();
#pragma unroll
    for (int reg = 0; reg < 4; ++reg) {
        int row = quad * 4 + reg;
        float S = 0.f, SS = 0.f;
#pragma unroll
        for (int t = 0; t < 8; ++t) { S += red[row][t][0]; SS += red[row][t][1]; }
        float mu = S * (1.f / 128.f);
        float var = fmaxf(SS * (1.f / 128.f) - mu * mu, 0.f);
        float rs = 1.f / sqrtf(var + 1e-5f);
        int col = wcol + l15;
        int i = ibase + row;
        float y = (x[reg] - mu) * rs * cg[col] + cbe[col];
        float sl = y / (1.f + __expf(-y));
        float rv = bf2f(res1b[((size_t)(b * N1 + 2 * i)) * COUT + col]);
        ch_out[((size_t)(b * N2 + i)) * COUT + col] = sl + rv;
    }
}

extern "C" void kernel_launch(void* const* d_in, const int* in_sizes, int n_in,
                              void* d_out, int out_size, void* d_ws, size_t ws_size,
                              hipStream_t stream) {
    const float* pos0 = (const float*)d_in[0];
    const float* ch0  = (const float*)d_in[1];
    const float* W1   = (const float*)d_in[2];
    const float* b1   = (const float*)d_in[3];
    const float* Wres = (const float*)d_in[4];
    const float* bres = (const float*)d_in[5];
    const float* W2   = (const float*)d_in[6];
    const float* b2   = (const float*)d_in[7];
    const float* g1   = (const float*)d_in[8];
    const float* be1  = (const float*)d_in[9];
    const float* g2   = (const float*)d_in[10];
    const float* be2  = (const float*)d_in[11];
    float* out = (float*)d_out;

    char* ws = (char*)d_ws;
    int*  knn1  = (int*)(ws);                      // 524288
    int*  knn2  = (int*)(ws + 524288);             // 262144
    u16*  ch0b  = (u16*)(ws + 786432);             // 2097152
    u16*  W1b   = (u16*)(ws + 2883584);            // 262144
    u16*  W2b   = (u16*)(ws + 3145728);            // 524288
    u16*  Wresb = (u16*)(ws + 3670016);            // 16384
    u16*  ch1b  = (u16*)(ws + 3686400);            // 2097152
    u16*  res1b = (u16*)(ws + 5783552);            // 2097152  (total ~7.9 MB)

    float* pos_out = out;          // [2,2048,3] fp32
    float* ch_out  = out + 12288;  // [2,2048,128] fp32

    knn_prep_kernel<<<2288, 256, 0, stream>>>(pos0, ch0, W1, W2, Wres,
                                              knn1, knn2, ch0b, W1b, W2b, Wresb, pos_out);
    conv1_kernel<<<512, 512, 0, stream>>>(ch0b, knn1, W1b, Wresb, b1, bres, g1, be1,
                                          ch1b, res1b);
    conv2_kernel<<<256, 512, 0, stream>>>(ch1b, knn2, W2b, b2, g2, be2, res1b, ch_out);
}

// Round 9
// 182.835 us; speedup vs baseline: 1.0401x; 1.0064x over previous
//
#include <hip/hip_runtime.h>
#include <cstdint>
#include <cstddef>

using u16 = unsigned short;
using u32 = unsigned int;
using u64 = unsigned long long;

typedef short bf16x8 __attribute__((ext_vector_type(8)));
typedef float f32x4 __attribute__((ext_vector_type(4)));
typedef float f4a __attribute__((ext_vector_type(4), aligned(4)));  // 4B-aligned vec4 load
typedef float f2a __attribute__((ext_vector_type(2), aligned(4)));  // 4B-aligned vec2 load

constexpr int N0 = 8192;
constexpr int N1 = 4096;
constexpr int N2 = 2048;
constexpr int COUT = 128;
constexpr int KNB = 16;

__device__ __forceinline__ float bf2f(u16 v) { return __uint_as_float(((u32)v) << 16); }
__device__ __forceinline__ u16 f2bf(float f) {  // round-to-nearest-even
    u32 u = __float_as_uint(f);
    return (u16)((u + 0x7fffu + ((u >> 16) & 1u)) >> 16);
}
__device__ __forceinline__ void cvt8(const float* __restrict__ src, u16* __restrict__ dst, int e) {
    float t0[8];
    *(float4*)t0 = *(const float4*)(src + e);
    *(float4*)(t0 + 4) = *(const float4*)(src + e + 4);
    u16 o[8];
#pragma unroll
    for (int q = 0; q < 8; ++q) o[q] = f2bf(t0[q]);
    *(uint4*)(dst + e) = *(uint4*)o;
}

// Distances must match the np reference bit-exactly: no FMA contraction, sequential sum.
__device__ __forceinline__ float dist2s(float cx, float cy, float cz,
                                        float px, float py, float pz) {
#pragma clang fp contract(off)
    float dx = cx - px;
    float dy = cy - py;
    float dz = cz - pz;
    float s = dx * dx;
    s = s + dy * dy;
    s = s + dz * dz;
    return s;
}

// ---- DPP cross-lane helpers (VALU pipe, no LDS traffic) ----
template <int CTRL>
__device__ __forceinline__ u64 dpp64(u64 v) {
    int lo = (int)(u32)v, hi = (int)(u32)(v >> 32);
    int plo = __builtin_amdgcn_update_dpp(0, lo, CTRL, 0xF, 0xF, true);
    int phi = __builtin_amdgcn_update_dpp(0, hi, CTRL, 0xF, 0xF, true);
    return (((u64)(u32)phi) << 32) | (u32)plo;
}
// row_shr:1 with bound_ctrl=1: lane L gets lane L-1; lane 0 of each 16-row gets 0.
__device__ __forceinline__ u64 dpp_prev_u64(u64 v) { return dpp64<0x111>(v); }

// wave-uniform broadcast via v_readlane (scalar result, no ds_bpermute on the chain)
__device__ __forceinline__ u32 rdlane(u32 v, int l) {
    return (u32)__builtin_amdgcn_readlane((int)v, l);
}

// ---------------- KNN scan, one wave, TWO centers, 128 candidates/step (2 per lane).
// Sorted-16 list in lanes 0..15 as u64 (d2_bits<<32)|idx — exact order + low-index tie-break.
// Structure PROVEN at R6 (best total 183). R9 delta: the 6 scalar candidate loads/step are
// replaced by dwordx4(+dwordx2) vector loads (candidate pair is contiguous memory), and the
// cut refresh is guarded by "any insert happened" (exact: no insert => cut unchanged).
template <int PSTRIDE>
__device__ __forceinline__ void knn_scan(const float* __restrict__ P,
                                         int c0row, int c1row, int cnt,
                                         int lane, u64& rk0, u64& rk1) {
    const float* c0p = P + (size_t)c0row * PSTRIDE;
    const float* c1p = P + (size_t)c1row * PSTRIDE;
    float c0x = c0p[0], c0y = c0p[1], c0z = c0p[2];
    float c1x = c1p[0], c1y = c1p[1], c1z = c1p[2];

    u64 key0, key1;
    {   // warm start: bitonic-sort first 64 points (xor 1/2/8 via DPP)
        const float* pp = P + (size_t)lane * PSTRIDE;
        float px = pp[0], py = pp[1], pz = pp[2];
        u64 k0 = (((u64)__float_as_uint(dist2s(c0x, c0y, c0z, px, py, pz))) << 32) | (u32)lane;
        u64 k1 = (((u64)__float_as_uint(dist2s(c1x, c1y, c1z, px, py, pz))) << 32) | (u32)lane;
#pragma unroll
        for (int kk = 2; kk <= 64; kk <<= 1)
#pragma unroll
            for (int jj = kk >> 1; jj > 0; jj >>= 1) {
                u64 o0, o1;
                if (jj == 1)      { o0 = dpp64<0xB1>(k0);  o1 = dpp64<0xB1>(k1); }
                else if (jj == 2) { o0 = dpp64<0x4E>(k0);  o1 = dpp64<0x4E>(k1); }
                else if (jj == 8) { o0 = dpp64<0x128>(k0); o1 = dpp64<0x128>(k1); }
                else              { o0 = __shfl_xor(k0, jj, 64); o1 = __shfl_xor(k1, jj, 64); }
                bool keepmin = (((lane & jj) == 0) == ((lane & kk) == 0));
                k0 = keepmin ? ((o0 < k0) ? o0 : k0) : ((o0 > k0) ? o0 : k0);
                k1 = keepmin ? ((o1 < k1) ? o1 : k1) : ((o1 > k1) ? o1 : k1);
            }
        key0 = k0; key1 = k1;
    }
    u32 cut0 = rdlane((u32)(key0 >> 32), 15);
    u32 cut1 = rdlane((u32)(key1 >> 32), 15);

    {   // half-step: candidates [64,128), one per lane
        const float* pp = P + (size_t)(64 + lane) * PSTRIDE;
        float px = pp[0], py = pp[1], pz = pp[2];
        u32 d0 = __float_as_uint(dist2s(c0x, c0y, c0z, px, py, pz));
        u32 d1 = __float_as_uint(dist2s(c1x, c1y, c1z, px, py, pz));
        u64 ball0 = __ballot(d0 <= cut0);
        u64 ball1 = __ballot(d1 <= cut1);
        bool any0 = ball0 != 0, any1 = ball1 != 0;
        while (ball0 | ball1) {
            if (ball0) {
                int src = __ffsll((unsigned long long)ball0) - 1;
                ball0 &= ball0 - 1;
                u64 nk = (((u64)rdlane(d0, src)) << 32) | (u32)(64 + src);
                u64 prev = dpp_prev_u64(key0);
                key0 = (nk < key0) ? ((nk < prev) ? prev : nk) : key0;
            }
            if (ball1) {
                int src = __ffsll((unsigned long long)ball1) - 1;
                ball1 &= ball1 - 1;
                u64 nk = (((u64)rdlane(d1, src)) << 32) | (u32)(64 + src);
                u64 prev = dpp_prev_u64(key1);
                key1 = (nk < key1) ? ((nk < prev) ? prev : nk) : key1;
            }
        }
        if (any0) cut0 = rdlane((u32)(key0 >> 32), 15);
        if (any1) cut1 = rdlane((u32)(key1 >> 32), 15);
    }

    // main loop: 128 candidates/step (2 per lane), starting at 128.
    // Lane's two candidates are adjacent rows -> vector loads:
    //   PSTRIDE=3: floats [0..5] = dwordx4 + dwordx2
    //   PSTRIDE=6: xyz at [0..2] and [6..8] = dwordx4 at p + dwordx4 at p+5
    constexpr int STEPF = 128 * PSTRIDE;
    int nstep = (cnt - 128) >> 7;
    const float* cur = P + (size_t)(128 + 2 * lane) * PSTRIDE;
    f4a va; f4a vb;
    if constexpr (PSTRIDE == 3) {
        va = *(const f4a*)cur;                       // x0 y0 z0 x1
        f2a t = *(const f2a*)(cur + 4);              // y1 z1
        vb.x = t.x; vb.y = t.y;
    } else {
        va = *(const f4a*)cur;                       // x0 y0 z0 .
        vb = *(const f4a*)(cur + 5);                 // . x1 y1 z1
    }
    for (int s = 0; s < nstep; ++s) {
        float cax, cay, caz, cbx, cby, cbz;
        if constexpr (PSTRIDE == 3) {
            cax = va.x; cay = va.y; caz = va.z;
            cbx = va.w; cby = vb.x; cbz = vb.y;
        } else {
            cax = va.x; cay = va.y; caz = va.z;
            cbx = vb.y; cby = vb.z; cbz = vb.w;
        }
        cur += STEPF;
        if (s + 1 < nstep) {
            if constexpr (PSTRIDE == 3) {
                va = *(const f4a*)cur;
                f2a t = *(const f2a*)(cur + 4);
                vb.x = t.x; vb.y = t.y;
            } else {
                va = *(const f4a*)cur;
                vb = *(const f4a*)(cur + 5);
            }
        }
        int sb = 128 + (s << 7);
        u32 da0 = __float_as_uint(dist2s(c0x, c0y, c0z, cax, cay, caz));
        u32 da1 = __float_as_uint(dist2s(c1x, c1y, c1z, cax, cay, caz));
        u32 db0 = __float_as_uint(dist2s(c0x, c0y, c0z, cbx, cby, cbz));
        u32 db1 = __float_as_uint(dist2s(c1x, c1y, c1z, cbx, cby, cbz));
        u64 ba0 = __ballot(da0 <= cut0);
        u64 bb0 = __ballot(db0 <= cut0);
        u64 ba1 = __ballot(da1 <= cut1);
        u64 bb1 = __ballot(db1 <= cut1);
        bool any0 = (ba0 | bb0) != 0, any1 = (ba1 | bb1) != 0;
        while (ba0 | bb0 | ba1 | bb1) {   // two independent key chains, 4 ballot streams
            if (ba0) {
                int src = __ffsll((unsigned long long)ba0) - 1;
                ba0 &= ba0 - 1;
                u64 nk = (((u64)rdlane(da0, src)) << 32) | (u32)(sb + 2 * src);
                u64 prev = dpp_prev_u64(key0);
                key0 = (nk < key0) ? ((nk < prev) ? prev : nk) : key0;
            }
            if (ba1) {
                int src = __ffsll((unsigned long long)ba1) - 1;
                ba1 &= ba1 - 1;
                u64 nk = (((u64)rdlane(da1, src)) << 32) | (u32)(sb + 2 * src);
                u64 prev = dpp_prev_u64(key1);
                key1 = (nk < key1) ? ((nk < prev) ? prev : nk) : key1;
            }
            if (bb0) {
                int src = __ffsll((unsigned long long)bb0) - 1;
                bb0 &= bb0 - 1;
                u64 nk = (((u64)rdlane(db0, src)) << 32) | (u32)(sb + 2 * src + 1);
                u64 prev = dpp_prev_u64(key0);
                key0 = (nk < key0) ? ((nk < prev) ? prev : nk) : key0;
            }
            if (bb1) {
                int src = __ffsll((unsigned long long)bb1) - 1;
                bb1 &= bb1 - 1;
                u64 nk = (((u64)rdlane(db1, src)) << 32) | (u32)(sb + 2 * src + 1);
                u64 prev = dpp_prev_u64(key1);
                key1 = (nk < key1) ? ((nk < prev) ? prev : nk) : key1;
            }
        }
        if (any0) cut0 = rdlane((u32)(key0 >> 32), 15);
        if (any1) cut1 = rdlane((u32)(key1 >> 32), 15);
    }
    rk0 = key0; rk1 = key1;
}

// ---------------- dispatch 1: knn1 (1024) + knn2 (512) + prep (752) = 2288 blocks --
// R6-proven routing: knn2's waves + prep's memory-bound copies fill knn1's idle issue
// slots; conv1 dispatch has no knn tail.
__global__ __launch_bounds__(256)
void knn_prep_kernel(const float* __restrict__ pos0, const float* __restrict__ ch0,
                     const float* __restrict__ W1, const float* __restrict__ W2,
                     const float* __restrict__ Wres,
                     int* __restrict__ knn1, int* __restrict__ knn2,
                     u16* __restrict__ ch0b, u16* __restrict__ W1b,
                     u16* __restrict__ W2b, u16* __restrict__ Wresb,
                     float* __restrict__ pos_out) {
    int blk = blockIdx.x, tid = threadIdx.x;
    int w = tid >> 6, lane = tid & 63;
    if (blk < 1024) {
        // knn1: one wave per center-pair, full 8192-candidate scan (stride 3 floats)
        int wave = blk * 4 + w;
        int batch = wave >> 11, pj = wave & 2047;
        const float* P = pos0 + (size_t)batch * N0 * 3;
        u64 key0, key1;
        knn_scan<3>(P, 4 * pj, 4 * pj + 2, N0, lane, key0, key1);
        if (lane < 16) {
            knn1[((size_t)(batch * N1 + 2 * pj)) * KNB + lane] = (int)(u32)key0;
            knn1[((size_t)(batch * N1 + 2 * pj + 1)) * KNB + lane] = (int)(u32)key1;
        }
    } else if (blk < 1536) {
        // knn2: one wave per center-pair, full 4096-candidate scan over level-1 rows (stride 6)
        int wave = (blk - 1024) * 4 + w;
        int batch = wave >> 10, pj = wave & 1023;
        const float* P = pos0 + (size_t)batch * N0 * 3;
        u64 key0, key1;
        knn_scan<6>(P, 4 * pj, 4 * pj + 2, N1, lane, key0, key1);
        if (lane < 16) {
            knn2[((size_t)(batch * N2 + 2 * pj)) * KNB + lane] = (int)(u32)key0;
            knn2[((size_t)(batch * N2 + 2 * pj + 1)) * KNB + lane] = (int)(u32)key1;
        }
    } else if (blk < 2048) {          // ch0 -> bf16 (1,048,576 elems)
        cvt8(ch0, ch0b, ((blk - 1536) * 256 + tid) * 8);
    } else if (blk < 2112) {          // W1 -> bf16 (131,072)
        cvt8(W1, W1b, ((blk - 2048) * 256 + tid) * 8);
    } else if (blk < 2240) {          // W2 -> bf16 (262,144)
        cvt8(W2, W2b, ((blk - 2112) * 256 + tid) * 8);
    } else if (blk < 2272) {          // Wres[c][o] -> Wresb[o][c] bf16 (8192 elems)
        int t = (blk - 2240) * 256 + tid;
        int o = t >> 6, c = t & 63;
        Wresb[o * 64 + c] = f2bf(Wres[(size_t)c * COUT + o]);
    } else {                          // pos_out copy: 4096 rows (16 blocks)
        int t = (blk - 2272) * 256 + tid;
        int b = t >> 11, r = t & 2047;
        const float* s = pos0 + ((size_t)(b * N0 + r * 4)) * 3;
        float* d = pos_out + ((size_t)(b * N2 + r)) * 3;
        d[0] = s[0]; d[1] = s[1]; d[2] = s[2];
    }
}

// ---------------- dispatch 2: conv1 W-direct, 512 blk x 512 thr (8 waves) ----------
// Weights load straight global->VGPR as MFMA B-fragments; only the gathered A-tile is
// LDS-staged, double-buffered, ONE barrier per K-chunk (R8 version, measured neutral
// vs R6's 256-thr variant — conv1 is off the critical path).
__global__ __launch_bounds__(512)
void conv1_kernel(const u16* __restrict__ ch0b, const int* __restrict__ knn1,
                  const u16* __restrict__ W1b, const u16* __restrict__ Wresb,
                  const float* __restrict__ b1, const float* __restrict__ bres,
                  const float* __restrict__ g1, const float* __restrict__ be1,
                  u16* __restrict__ ch1b, u16* __restrict__ res1b) {
    __shared__ u16 As[2][16][72];     // double-buffered A tile: 16 rows x 64 bf16 (+8 pad)
    __shared__ int knnr[16][16];
    __shared__ float red[16][8][2];
    __shared__ float cb[128], cg[128], cbe[128], cbr[128];

    int blk = blockIdx.x, tid = threadIdx.x;   // 0..511
    int b = blk >> 8, g = blk & 255;
    int jbase = g * 16;

    if (tid < 128) { cb[tid] = b1[tid]; cg[tid] = g1[tid]; cbe[tid] = be1[tid]; cbr[tid] = bres[tid]; }
    if (tid < 256) {   // 256 knn ints
        int r = tid >> 4, k = tid & 15;
        knnr[r][k] = knn1[((size_t)(b * N1 + jbase + r)) * KNB + k];
    }
    __syncthreads();

    int w = tid >> 6, lane = tid & 63, quad = lane >> 4, l15 = lane & 15;
    int wcol = w * 16;
    int ar = tid >> 5, ap = tid & 31;     // A staging: 16 rows x 32 chunks of 4B

    f32x4 acc = {0, 0, 0, 0};
    f32x4 racc = {0, 0, 0, 0};

    // per-lane W fragment base (col wcol+l15); frag(ks) at kn: base + kn*64 + ks*32
    const u16* wbase = W1b + (size_t)(wcol + l15) * 1024 + quad * 8;

    // prologue: prefetch chunk 0
    u32 aR = *((const u32*)(ch0b + ((size_t)(b * N0 + knnr[ar][0])) * 64) + ap);
    uint4 wcur[2] = { *(const uint4*)wbase, *(const uint4*)(wbase + 32) };

    int pb = 0;
    for (int kn = 0; kn < 17; ++kn) {     // 16 neighbor chunks + 1 residual chunk
        *(u32*)&As[pb][ar][ap * 2] = aR;
        __syncthreads();
        uint4 wnxt[2];
        if (kn < 16) {  // prefetch next chunk (kn==15 -> residual sources)
            int nidx = (kn < 15) ? knnr[ar][kn + 1] : 2 * (jbase + ar);
            aR = *((const u32*)(ch0b + ((size_t)(b * N0 + nidx)) * 64) + ap);
            if (kn < 15) {
                const u16* p = wbase + (kn + 1) * 64;
                wnxt[0] = *(const uint4*)p; wnxt[1] = *(const uint4*)(p + 32);
            } else {
                const u16* p = Wresb + (size_t)(wcol + l15) * 64 + quad * 8;
                wnxt[0] = *(const uint4*)p; wnxt[1] = *(const uint4*)(p + 32);
            }
        }
        if (kn < 16) {
#pragma unroll
            for (int ks = 0; ks < 2; ++ks) {
                bf16x8 af = *(const bf16x8*)&As[pb][l15][ks * 32 + quad * 8];
                acc = __builtin_amdgcn_mfma_f32_16x16x32_bf16(af, *(const bf16x8*)&wcur[ks], acc, 0, 0, 0);
            }
        } else {
#pragma unroll
            for (int ks = 0; ks < 2; ++ks) {
                bf16x8 af = *(const bf16x8*)&As[pb][l15][ks * 32 + quad * 8];
                racc = __builtin_amdgcn_mfma_f32_16x16x32_bf16(af, *(const bf16x8*)&wcur[ks], racc, 0, 0, 0);
            }
        }
        if (kn < 16) { wcur[0] = wnxt[0]; wcur[1] = wnxt[1]; }
        pb ^= 1;
    }

    // epilogue: bias + LN(+SiLU) on conv acc; bias on residual; both stored bf16
    float x[4], s[4], ss[4];
#pragma unroll
    for (int reg = 0; reg < 4; ++reg) {
        int col = wcol + l15;
        float v = acc[reg] + cb[col];
        x[reg] = v; s[reg] = v; ss[reg] = v * v;
    }
#pragma unroll
    for (int m = 1; m < 16; m <<= 1)
#pragma unroll
        for (int reg = 0; reg < 4; ++reg) {
            s[reg] += __shfl_xor(s[reg], m, 64);
            ss[reg] += __shfl_xor(ss[reg], m, 64);
        }
    if (l15 == 0) {
#pragma unroll
        for (int reg = 0; reg < 4; ++reg) {
            red[quad * 4 + reg][w][0] = s[reg];
            red[quad * 4 + reg][w][1] = ss[reg];
        }
    }
    __syncthreads();
#pragma unroll
    for (int reg = 0; reg < 4; ++reg) {
        int row = quad * 4 + reg;
        float S = 0.f, SS = 0.f;
#pragma unroll
        for (int t = 0; t < 8; ++t) { S += red[row][t][0]; SS += red[row][t][1]; }
        float mu = S * (1.f / 128.f);
        float var = fmaxf(SS * (1.f / 128.f) - mu * mu, 0.f);
        float rs = 1.f / sqrtf(var + 1e-5f);
        int col = wcol + l15;
        size_t off = ((size_t)(b * N1 + jbase + row)) * COUT + col;
        float y = (x[reg] - mu) * rs * cg[col] + cbe[col];
        ch1b[off] = f2bf(y / (1.f + __expf(-y)));
        res1b[off] = f2bf(racc[reg] + cbr[col]);
    }
}

// ---------------- dispatch 3: conv2 W-direct, K=2048, 512 thr (8 waves), M=16 ------
__global__ __launch_bounds__(512)
void conv2_kernel(const u16* __restrict__ ch1b, const int* __restrict__ knn2,
                  const u16* __restrict__ W2b, const float* __restrict__ b2,
                  const float* __restrict__ g2, const float* __restrict__ be2,
                  const u16* __restrict__ res1b, float* __restrict__ ch_out) {
    __shared__ u16 As[2][16][136];    // double-buffered A tile: 16 rows x 128 bf16 (+8 pad)
    __shared__ int knnr[16][16];
    __shared__ float red[16][8][2];
    __shared__ float cb[128], cg[128], cbe[128];

    int tid = threadIdx.x;            // 0..511
    int b = blockIdx.x >> 7, g = blockIdx.x & 127;
    int ibase = g * 16;

    if (tid < 128) { cb[tid] = b2[tid]; cg[tid] = g2[tid]; cbe[tid] = be2[tid]; }
    if (tid < 256) {
        int r = tid >> 4, k = tid & 15;
        knnr[r][k] = knn2[((size_t)(b * N2 + ibase + r)) * KNB + k];
    }
    __syncthreads();

    int w = tid >> 6, lane = tid & 63, quad = lane >> 4, l15 = lane & 15;
    int wcol = w * 16;
    int ar = tid >> 5, ap = tid & 31;     // A staging: 16 rows x 32 chunks of 8B

    f32x4 acc = {0, 0, 0, 0};

    // per-lane W fragment base (col wcol+l15); frag(ks) at kn: base + kn*128 + ks*32
    const u16* wbase = W2b + (size_t)(wcol + l15) * 2048 + quad * 8;

    uint2 aR = *((const uint2*)(ch1b + ((size_t)(b * N1 + knnr[ar][0])) * COUT) + ap);
    uint4 wcur[4] = { *(const uint4*)wbase, *(const uint4*)(wbase + 32),
                      *(const uint4*)(wbase + 64), *(const uint4*)(wbase + 96) };

    int pb = 0;
    for (int kn = 0; kn < 16; ++kn) {
        *(uint2*)&As[pb][ar][ap * 4] = aR;
        __syncthreads();
        uint4 wnxt[4];
        if (kn < 15) {
            aR = *((const uint2*)(ch1b + ((size_t)(b * N1 + knnr[ar][kn + 1])) * COUT) + ap);
            const u16* p = wbase + (kn + 1) * 128;
            wnxt[0] = *(const uint4*)p;        wnxt[1] = *(const uint4*)(p + 32);
            wnxt[2] = *(const uint4*)(p + 64); wnxt[3] = *(const uint4*)(p + 96);
        }
#pragma unroll
        for (int ks = 0; ks < 4; ++ks) {
            bf16x8 af = *(const bf16x8*)&As[pb][l15][ks * 32 + quad * 8];
            acc = __builtin_amdgcn_mfma_f32_16x16x32_bf16(af, *(const bf16x8*)&wcur[ks], acc, 0, 0, 0);
        }
        if (kn < 15) {
            wcur[0] = wnxt[0]; wcur[1] = wnxt[1]; wcur[2] = wnxt[2]; wcur[3] = wnxt[3];
        }
        pb ^= 1;
    }

    float x[4], s[4], ss[4];
#pragma unroll
    for (int reg = 0; reg < 4; ++reg) {
        int col = wcol + l15;
        float v = acc[reg] + cb[col];
        x[reg] = v; s[reg] = v; ss[reg] = v * v;
    }
#pragma unroll
    for (int m = 1; m < 16; m <<= 1)
#pragma unroll
        for (int reg = 0; reg < 4; ++reg) {
            s[reg] += __shfl_xor(s[reg], m, 64);
            ss[reg] += __shfl_xor(ss[reg], m, 64);
        }
    if (l15 == 0) {
#pragma unroll
        for (int reg = 0; reg < 4; ++reg) {
            red[quad * 4 + reg][w][0] = s[reg];
            red[quad * 4 + reg][w][1] = ss[reg];
        }
    }
    __syncthreads();
#pragma unroll
    for (int reg = 0; reg < 4; ++reg) {
        int row = quad * 4 + reg;
        float S = 0.f, SS = 0.f;
#pragma unroll
        for (int t = 0; t < 8; ++t) { S += red[row][t][0]; SS += red[row][t][1]; }
        float mu = S * (1.f / 128.f);
        float var = fmaxf(SS * (1.f / 128.f) - mu * mu, 0.f);
        float rs = 1.f / sqrtf(var + 1e-5f);
        int col = wcol + l15;
        int i = ibase + row;
        float y = (x[reg] - mu) * rs * cg[col] + cbe[col];
        float sl = y / (1.f + __expf(-y));
        float rv = bf2f(res1b[((size_t)(b * N1 + 2 * i)) * COUT + col]);
        ch_out[((size_t)(b * N2 + i)) * COUT + col] = sl + rv;
    }
}

extern "C" void kernel_launch(void* const* d_in, const int* in_sizes, int n_in,
                              void* d_out, int out_size, void* d_ws, size_t ws_size,
                              hipStream_t stream) {
    const float* pos0 = (const float*)d_in[0];
    const float* ch0  = (const float*)d_in[1];
    const float* W1   = (const float*)d_in[2];
    const float* b1   = (const float*)d_in[3];
    const float* Wres = (const float*)d_in[4];
    const float* bres = (const float*)d_in[5];
    const float* W2   = (const float*)d_in[6];
    const float* b2   = (const float*)d_in[7];
    const float* g1   = (const float*)d_in[8];
    const float* be1  = (const float*)d_in[9];
    const float* g2   = (const float*)d_in[10];
    const float* be2  = (const float*)d_in[11];
    float* out = (float*)d_out;

    char* ws = (char*)d_ws;
    int*  knn1  = (int*)(ws);                      // 524288
    int*  knn2  = (int*)(ws + 524288);             // 262144
    u16*  ch0b  = (u16*)(ws + 786432);             // 2097152
    u16*  W1b   = (u16*)(ws + 2883584);            // 262144
    u16*  W2b   = (u16*)(ws + 3145728);            // 524288
    u16*  Wresb = (u16*)(ws + 3670016);            // 16384
    u16*  ch1b  = (u16*)(ws + 3686400);            // 2097152
    u16*  res1b = (u16*)(ws + 5783552);            // 2097152  (total ~7.9 MB)

    float* pos_out = out;          // [2,2048,3] fp32
    float* ch_out  = out + 12288;  // [2,2048,128] fp32

    knn_prep_kernel<<<2288, 256, 0, stream>>>(pos0, ch0, W1, W2, Wres,
                                              knn1, knn2, ch0b, W1b, W2b, Wresb, pos_out);
    conv1_kernel<<<512, 512, 0, stream>>>(ch0b, knn1, W1b, Wresb, b1, bres, g1, be1,
                                          ch1b, res1b);
    conv2_kernel<<<256, 512, 0, stream>>>(ch1b, knn2, W2b, b2, g2, be2, res1b, ch_out);
}